// Round 5
// baseline (39691.910 us; speedup 1.0000x reference)
//
#include <hip/hip_runtime.h>
#include <hip/hip_cooperative_groups.h>
#include <math.h>

namespace cg = cooperative_groups;

// NTM recurrence. Cooperative persistent kernel (grid-stride phases, occupancy-guarded
// launch) with a non-cooperative per-phase fallback. GEMMs: 3-product 2-plane bf16-split MFMA.
// B=256 T=128 I=512 H=512 N=1024 M=512 O=512
#define B_ 256
#define T_ 128
#define I_ 512
#define H_ 512
#define N_ 1024
#define M_ 512
#define O_ 512
#define EPS_ 1e-8f

typedef unsigned short u16;
typedef __attribute__((ext_vector_type(8))) short v8s;
typedef __attribute__((ext_vector_type(4))) float v4f;

#define MFMA(a, b, c) __builtin_amdgcn_mfma_f32_16x16x32_bf16(a, b, c, 0, 0, 0)

// plane strides (elements)
#define PL_BIG 1310720  // BigT [2560][512]: 0-511 Whw_k, 512-1023 Whr_k, 1024-1535 Wo, 1536-2559 Wea
#define PL_WXT 262144   // WxT  [512][512]
#define PL_WRT 262144   // WrT  [512][512]
#define PL_MEM 524288   // mem  [1024][512] / memT [512][1024]
#define PL_W   262144   // wwT  [1024][256]
#define PL_H   131072   // h0 planes [256][512], eT/aT [512][256]
#define PL_KH  262144   // kh [512][512]

// ---------------- scalar helpers ----------------
__device__ __forceinline__ float sigm_(float x) { return 1.f / (1.f + expf(-x)); }
__device__ __forceinline__ float softplus_(float x) { return x > 20.f ? x : log1pf(expf(x)); }
__device__ __forceinline__ u16 f2bf(float f) {
    unsigned u = __float_as_uint(f);
    u += 0x7fffu + ((u >> 16) & 1u);
    return (u16)(u >> 16);
}
__device__ __forceinline__ float bf2f(u16 h) { return __uint_as_float((unsigned)h << 16); }
__device__ __forceinline__ void split2(float f, u16& h, u16& m) {
    h = f2bf(f);
    m = f2bf(f - bf2f(h));
}
__device__ __forceinline__ void mfma3(v4f& c, v8s a0, v8s a1, v8s b0, v8s b1) {
    c = MFMA(a0, b0, c);
    c = MFMA(a0, b1, c);
    c = MFMA(a1, b0, c);
}

__device__ __forceinline__ float wave_sum_(float v) {
#pragma unroll
    for (int o = 32; o > 0; o >>= 1) v += __shfl_down(v, o);
    return v;
}
__device__ __forceinline__ float wave_max_(float v) {
#pragma unroll
    for (int o = 32; o > 0; o >>= 1) v = fmaxf(v, __shfl_down(v, o));
    return v;
}
__device__ float block_sum_(float v, float* s) {
    int lane = threadIdx.x & 63, wid = threadIdx.x >> 6, nw = blockDim.x >> 6;
    v = wave_sum_(v);
    if (lane == 0) s[wid] = v;
    __syncthreads();
    float r = (threadIdx.x < nw) ? s[threadIdx.x] : 0.f;
    if (wid == 0) { r = wave_sum_(r); if (lane == 0) s[0] = r; }
    __syncthreads();
    float out = s[0];
    __syncthreads();
    return out;
}
__device__ float block_max_(float v, float* s) {
    int lane = threadIdx.x & 63, wid = threadIdx.x >> 6, nw = blockDim.x >> 6;
    v = wave_max_(v);
    if (lane == 0) s[wid] = v;
    __syncthreads();
    float r = (threadIdx.x < nw) ? s[threadIdx.x] : -3.4e38f;
    if (wid == 0) { r = wave_max_(r); if (lane == 0) s[0] = r; }
    __syncthreads();
    float out = s[0];
    __syncthreads();
    return out;
}

// ---------------- shared-memory block (one instance per block) ----------------
struct Sh {
    u16 sA[2 * 32 * 40];
    u16 sB[2 * 64 * 40];
    u16 sB2[2 * 64 * 40];
    float wgs[N_];
    float red[8];
    float ssq[32];
};

struct MArgs {
    const float *bea, *bh, *bhw, *bhr, *bo, *w6w, *w6r;
    const u16 *BigT, *WrT;
    u16 *mem_pl, *memT_pl, *wwT_pl, *eT, *aT, *kh;
    float *memf, *wwf, *wrf, *r_acc, *h_acc, *xwx_cur, *logits, *ssqp, *outbuf;
};

// ================= phase bodies (block-level units) =================
// P1: u<256 -> memupd tile; u>=256 -> zero r_acc/h_acc + copy xwx row (u-256)
__device__ void phase1(const MArgs& A, Sh& sh, int u, int t) {
    const int tid = threadIdx.x;
    if (u >= 256) {
        int j = u - 256;
        if (tid < 128) {
            float4 z = make_float4(0.f, 0.f, 0.f, 0.f);
            *(float4*)&A.r_acc[(size_t)j * 512 + tid * 4] = z;
            *(float4*)&A.h_acc[(size_t)j * 512 + tid * 4] = z;
            *(float4*)&A.xwx_cur[(size_t)j * 512 + tid * 4] =
                *(const float4*)&A.outbuf[((size_t)j * T_ + t) * O_ + tid * 4];
        }
        return;
    }
    const int lane = tid & 63, w = tid >> 6, wy = w >> 1, wx = w & 1, q = lane >> 4, l15 = lane & 15;
    const int n0 = (u >> 3) * 32, m0c = (u & 7) * 64;
    if (tid < 32) sh.ssq[tid] = 0.f;
    const int ap = tid >> 7, ar = (tid >> 2) & 31, akg = tid & 3;
    uint4 pa, pb[2], pc[2];
    auto ld = [&](int k0) {
        pa = *(const uint4*)(A.wwT_pl + (size_t)ap * PL_W + (size_t)(n0 + ar) * B_ + k0 + akg * 8);
#pragma unroll
        for (int j = 0; j < 2; j++) {
            int s = j * 256 + tid, p = s >> 8, rr = (s >> 2) & 63, kg = s & 3;
            pb[j] = *(const uint4*)(A.eT + (size_t)p * PL_H + (size_t)(m0c + rr) * B_ + k0 + kg * 8);
            pc[j] = *(const uint4*)(A.aT + (size_t)p * PL_H + (size_t)(m0c + rr) * B_ + k0 + kg * 8);
        }
    };
    v4f ae[2] = {}, aa[2] = {};
    ld(0);
    for (int k0 = 0; k0 < B_; k0 += 32) {
        *(uint4*)&sh.sA[(ap * 32 + ar) * 40 + akg * 8] = pa;
#pragma unroll
        for (int j = 0; j < 2; j++) {
            int s = j * 256 + tid, p = s >> 8, rr = (s >> 2) & 63, kg = s & 3;
            *(uint4*)&sh.sB[(p * 64 + rr) * 40 + kg * 8] = pb[j];
            *(uint4*)&sh.sB2[(p * 64 + rr) * 40 + kg * 8] = pc[j];
        }
        __syncthreads();
        if (k0 + 32 < B_) ld(k0 + 32);
        v8s a0 = *(const v8s*)&sh.sA[(0 * 32 + wy * 16 + l15) * 40 + q * 8];
        v8s a1 = *(const v8s*)&sh.sA[(1 * 32 + wy * 16 + l15) * 40 + q * 8];
#pragma unroll
        for (int nt = 0; nt < 2; nt++) {
            int rb = wx * 32 + nt * 16 + l15;
            v8s e0 = *(const v8s*)&sh.sB[(0 * 64 + rb) * 40 + q * 8];
            v8s e1 = *(const v8s*)&sh.sB[(1 * 64 + rb) * 40 + q * 8];
            v8s c0 = *(const v8s*)&sh.sB2[(0 * 64 + rb) * 40 + q * 8];
            v8s c1 = *(const v8s*)&sh.sB2[(1 * 64 + rb) * 40 + q * 8];
            mfma3(ae[nt], a0, a1, e0, e1);
            mfma3(aa[nt], a0, a1, c0, c1);
        }
        __syncthreads();
    }
    const float invB = 1.f / 256.f;
#pragma unroll
    for (int nt = 0; nt < 2; nt++) {
        int n = n0 + wy * 16 + q * 4;
        int m = m0c + wx * 32 + nt * 16 + l15;
        u16 hv[4][2];
#pragma unroll
        for (int r = 0; r < 4; r++) {
            size_t idx = (size_t)(n + r) * M_ + m;
            float old = A.memf[idx];
            float nv = old * (1.f - ae[nt][r] * invB) + aa[nt][r] * invB;
            A.memf[idx] = nv;
            u16 h, mm; split2(nv, h, mm);
            A.mem_pl[idx] = h; A.mem_pl[PL_MEM + idx] = mm;
            hv[r][0] = h; hv[r][1] = mm;
            atomicAdd(&sh.ssq[n + r - n0], nv * nv);
        }
        size_t tb = (size_t)m * N_ + n;
        *(ushort4*)&A.memT_pl[tb] = make_ushort4(hv[0][0], hv[1][0], hv[2][0], hv[3][0]);
        *(ushort4*)&A.memT_pl[PL_MEM + tb] = make_ushort4(hv[0][1], hv[1][1], hv[2][1], hv[3][1]);
    }
    __syncthreads();
    if (tid < 32) A.ssqp[(size_t)(n0 + tid) * 8 + (u & 7)] = sh.ssq[tid];
}

// P2: r_acc += (wr @ memT) split-K4, A split2 from fp32 on the fly
__device__ void phase2(const MArgs& A, Sh& sh, int u) {
    const int tid = threadIdx.x;
    const int lane = tid & 63, w = tid >> 6, wy = w >> 1, wx = w & 1, q = lane >> 4, l15 = lane & 15;
    const int tile = u >> 2, kc = u & 3;
    const int b0 = (tile >> 3) * 32, m0c = (tile & 7) * 64, kb = kc * 256;
    const int ar = tid >> 3, akg = tid & 7;
    float4 fa; uint4 pb[2];
    auto ld = [&](int k0) {
        fa = *(const float4*)(A.wrf + (size_t)(b0 + ar) * N_ + k0 + akg * 4);
#pragma unroll
        for (int j = 0; j < 2; j++) {
            int s = j * 256 + tid, p = s >> 8, rr = (s >> 2) & 63, kg = s & 3;
            pb[j] = *(const uint4*)(A.memT_pl + (size_t)p * PL_MEM + (size_t)(m0c + rr) * N_ + k0 + kg * 8);
        }
    };
    v4f acc[2] = {};
    ld(kb);
    for (int k0 = kb; k0 < kb + 256; k0 += 32) {
        u16 h0, l0, h1, l1, h2, l2, h3, l3;
        split2(fa.x, h0, l0); split2(fa.y, h1, l1); split2(fa.z, h2, l2); split2(fa.w, h3, l3);
        *(ushort4*)&sh.sA[(0 * 32 + ar) * 40 + akg * 4] = make_ushort4(h0, h1, h2, h3);
        *(ushort4*)&sh.sA[(1 * 32 + ar) * 40 + akg * 4] = make_ushort4(l0, l1, l2, l3);
#pragma unroll
        for (int j = 0; j < 2; j++) {
            int s = j * 256 + tid, p = s >> 8, rr = (s >> 2) & 63, kg = s & 3;
            *(uint4*)&sh.sB[(p * 64 + rr) * 40 + kg * 8] = pb[j];
        }
        __syncthreads();
        if (k0 + 32 < kb + 256) ld(k0 + 32);
        v8s a0 = *(const v8s*)&sh.sA[(0 * 32 + wy * 16 + l15) * 40 + q * 8];
        v8s a1 = *(const v8s*)&sh.sA[(1 * 32 + wy * 16 + l15) * 40 + q * 8];
#pragma unroll
        for (int nt = 0; nt < 2; nt++) {
            int rb = wx * 32 + nt * 16 + l15;
            v8s b0v = *(const v8s*)&sh.sB[(0 * 64 + rb) * 40 + q * 8];
            v8s b1v = *(const v8s*)&sh.sB[(1 * 64 + rb) * 40 + q * 8];
            mfma3(acc[nt], a0, a1, b0v, b1v);
        }
        __syncthreads();
    }
#pragma unroll
    for (int nt = 0; nt < 2; nt++)
#pragma unroll
        for (int r = 0; r < 4; r++)
            atomicAdd(&A.r_acc[(size_t)(b0 + wy * 16 + q * 4 + r) * M_ + m0c + wx * 32 + nt * 16 + l15],
                      acc[nt][r]);
}

// P3: h_acc += (r_acc @ WrT) split-K4
__device__ void phase3(const MArgs& A, Sh& sh, int u) {
    const int tid = threadIdx.x;
    const int lane = tid & 63, w = tid >> 6, wy = w >> 1, wx = w & 1, q = lane >> 4, l15 = lane & 15;
    const int tile = u >> 2, kc = u & 3;
    const int b0 = (tile >> 3) * 32, h0c = (tile & 7) * 64, kb = kc * 128;
    const int ar = tid >> 3, akg = tid & 7;
    float4 fa; uint4 pb[2];
    auto ld = [&](int k0) {
        fa = *(const float4*)(A.r_acc + (size_t)(b0 + ar) * M_ + k0 + akg * 4);
#pragma unroll
        for (int j = 0; j < 2; j++) {
            int s = j * 256 + tid, p = s >> 8, rr = (s >> 2) & 63, kg = s & 3;
            pb[j] = *(const uint4*)(A.WrT + (size_t)p * PL_WRT + (size_t)(h0c + rr) * M_ + k0 + kg * 8);
        }
    };
    v4f acc[2] = {};
    ld(kb);
    for (int k0 = kb; k0 < kb + 128; k0 += 32) {
        u16 h0, l0, h1, l1, h2, l2, h3, l3;
        split2(fa.x, h0, l0); split2(fa.y, h1, l1); split2(fa.z, h2, l2); split2(fa.w, h3, l3);
        *(ushort4*)&sh.sA[(0 * 32 + ar) * 40 + akg * 4] = make_ushort4(h0, h1, h2, h3);
        *(ushort4*)&sh.sA[(1 * 32 + ar) * 40 + akg * 4] = make_ushort4(l0, l1, l2, l3);
#pragma unroll
        for (int j = 0; j < 2; j++) {
            int s = j * 256 + tid, p = s >> 8, rr = (s >> 2) & 63, kg = s & 3;
            *(uint4*)&sh.sB[(p * 64 + rr) * 40 + kg * 8] = pb[j];
        }
        __syncthreads();
        if (k0 + 32 < kb + 128) ld(k0 + 32);
        v8s a0 = *(const v8s*)&sh.sA[(0 * 32 + wy * 16 + l15) * 40 + q * 8];
        v8s a1 = *(const v8s*)&sh.sA[(1 * 32 + wy * 16 + l15) * 40 + q * 8];
#pragma unroll
        for (int nt = 0; nt < 2; nt++) {
            int rb = wx * 32 + nt * 16 + l15;
            v8s b0v = *(const v8s*)&sh.sB[(0 * 64 + rb) * 40 + q * 8];
            v8s b1v = *(const v8s*)&sh.sB[(1 * 64 + rb) * 40 + q * 8];
            mfma3(acc[nt], a0, a1, b0v, b1v);
        }
        __syncthreads();
    }
#pragma unroll
    for (int nt = 0; nt < 2; nt++)
#pragma unroll
        for (int r = 0; r < 4; r++)
            atomicAdd(&A.h_acc[(size_t)(b0 + wy * 16 + q * 4 + r) * H_ + h0c + wx * 32 + nt * 16 + l15],
                      acc[nt][r]);
}

// P4: h=tanh(h_acc+xwx+bh) on the fly; h @ BigT -> keys | out_t | ea_next
__device__ void phase4(const MArgs& A, Sh& sh, int u, int t) {
    const int tid = threadIdx.x;
    const int lane = tid & 63, w = tid >> 6, wy = w >> 1, wx = w & 1, q = lane >> 4, l15 = lane & 15;
    const int b0 = (u & 7) * 32, c0 = (u >> 3) * 64;
    const int ar = tid >> 3, akg = tid & 7;
    float4 fh, fx, fb; uint4 pb[2];
    auto ld = [&](int k0) {
        fh = *(const float4*)(A.h_acc + (size_t)(b0 + ar) * H_ + k0 + akg * 4);
        fx = *(const float4*)(A.xwx_cur + (size_t)(b0 + ar) * H_ + k0 + akg * 4);
        fb = *(const float4*)(A.bh + k0 + akg * 4);
#pragma unroll
        for (int j = 0; j < 2; j++) {
            int s = j * 256 + tid, p = s >> 8, rr = (s >> 2) & 63, kg = s & 3;
            pb[j] = *(const uint4*)(A.BigT + (size_t)p * PL_BIG + (size_t)(c0 + rr) * H_ + k0 + kg * 8);
        }
    };
    v4f acc[2] = {};
    ld(0);
    for (int k0 = 0; k0 < H_; k0 += 32) {
        float v0 = tanhf(fh.x + fx.x + fb.x), v1 = tanhf(fh.y + fx.y + fb.y);
        float v2 = tanhf(fh.z + fx.z + fb.z), v3 = tanhf(fh.w + fx.w + fb.w);
        u16 h0, l0, h1, l1, h2, l2, h3, l3;
        split2(v0, h0, l0); split2(v1, h1, l1); split2(v2, h2, l2); split2(v3, h3, l3);
        *(ushort4*)&sh.sA[(0 * 32 + ar) * 40 + akg * 4] = make_ushort4(h0, h1, h2, h3);
        *(ushort4*)&sh.sA[(1 * 32 + ar) * 40 + akg * 4] = make_ushort4(l0, l1, l2, l3);
#pragma unroll
        for (int j = 0; j < 2; j++) {
            int s = j * 256 + tid, p = s >> 8, rr = (s >> 2) & 63, kg = s & 3;
            *(uint4*)&sh.sB[(p * 64 + rr) * 40 + kg * 8] = pb[j];
        }
        __syncthreads();
        if (k0 + 32 < H_) ld(k0 + 32);
        v8s a0 = *(const v8s*)&sh.sA[(0 * 32 + wy * 16 + l15) * 40 + q * 8];
        v8s a1 = *(const v8s*)&sh.sA[(1 * 32 + wy * 16 + l15) * 40 + q * 8];
#pragma unroll
        for (int nt = 0; nt < 2; nt++) {
            int rb = wx * 32 + nt * 16 + l15;
            v8s b0v = *(const v8s*)&sh.sB[(0 * 64 + rb) * 40 + q * 8];
            v8s b1v = *(const v8s*)&sh.sB[(1 * 64 + rb) * 40 + q * 8];
            mfma3(acc[nt], a0, a1, b0v, b1v);
        }
        __syncthreads();
    }
#pragma unroll
    for (int nt = 0; nt < 2; nt++) {
        int c = c0 + wx * 32 + nt * 16 + l15;
        int bb = b0 + wy * 16 + q * 4;
        if (c < 1024) {
            int head = c >> 9, key = c & 511;
            const float* bias = head ? A.bhr : A.bhw;
#pragma unroll
            for (int r = 0; r < 4; r++) {
                float val = tanhf(acc[nt][r] + bias[key]);
                size_t idx = (size_t)(head * 256 + bb + r) * M_ + key;
                u16 h, m; split2(val, h, m);
                A.kh[idx] = h; A.kh[PL_KH + idx] = m;
            }
        } else if (c < 1536) {
            int o = c - 1024;
#pragma unroll
            for (int r = 0; r < 4; r++)
                A.outbuf[((size_t)(bb + r) * T_ + t) * O_ + o] = sigm_(acc[nt][r] + A.bo[o]);
        } else {
            int m = c - 1536;
#pragma unroll
            for (int r = 0; r < 4; r++) {
                float val = acc[nt][r] + A.bea[m];
                u16* dst;
                if (m < M_) { val = sigm_(val); dst = A.eT + (size_t)m * B_ + bb + r; }
                else        { val = tanhf(val); dst = A.aT + (size_t)(m - M_) * B_ + bb + r; }
                u16 h, mm; split2(val, h, mm);
                dst[0] = h; dst[PL_H] = mm;
            }
        }
    }
}

// P5: logits = (kh @ mem^T) * invn
__device__ void phase5(const MArgs& A, Sh& sh, int u) {
    const int tid = threadIdx.x;
    const int lane = tid & 63, w = tid >> 6, wy = w >> 1, wx = w & 1, q = lane >> 4, l15 = lane & 15;
    const int r0 = (u >> 4) * 32, n0 = (u & 15) * 64;
    const int ap = tid >> 7, ar = (tid >> 2) & 31, akg = tid & 3;
    uint4 pa, pb[2];
    auto ld = [&](int k0) {
        pa = *(const uint4*)(A.kh + (size_t)ap * PL_KH + (size_t)(r0 + ar) * M_ + k0 + akg * 8);
#pragma unroll
        for (int j = 0; j < 2; j++) {
            int s = j * 256 + tid, p = s >> 8, rr = (s >> 2) & 63, kg = s & 3;
            pb[j] = *(const uint4*)(A.mem_pl + (size_t)p * PL_MEM + (size_t)(n0 + rr) * M_ + k0 + kg * 8);
        }
    };
    v4f acc[2] = {};
    ld(0);
    for (int k0 = 0; k0 < M_; k0 += 32) {
        *(uint4*)&sh.sA[(ap * 32 + ar) * 40 + akg * 8] = pa;
#pragma unroll
        for (int j = 0; j < 2; j++) {
            int s = j * 256 + tid, p = s >> 8, rr = (s >> 2) & 63, kg = s & 3;
            *(uint4*)&sh.sB[(p * 64 + rr) * 40 + kg * 8] = pb[j];
        }
        __syncthreads();
        if (k0 + 32 < M_) ld(k0 + 32);
        v8s a0 = *(const v8s*)&sh.sA[(0 * 32 + wy * 16 + l15) * 40 + q * 8];
        v8s a1 = *(const v8s*)&sh.sA[(1 * 32 + wy * 16 + l15) * 40 + q * 8];
#pragma unroll
        for (int nt = 0; nt < 2; nt++) {
            int rb = wx * 32 + nt * 16 + l15;
            v8s b0v = *(const v8s*)&sh.sB[(0 * 64 + rb) * 40 + q * 8];
            v8s b1v = *(const v8s*)&sh.sB[(1 * 64 + rb) * 40 + q * 8];
            mfma3(acc[nt], a0, a1, b0v, b1v);
        }
        __syncthreads();
    }
#pragma unroll
    for (int nt = 0; nt < 2; nt++) {
        int c = n0 + wx * 32 + nt * 16 + l15;
        float s = 0.f;
#pragma unroll
        for (int j2 = 0; j2 < 8; j2++) s += A.ssqp[(size_t)c * 8 + j2];
        float invn = 1.f / (sqrtf(s) + EPS_);
        int rr0 = r0 + wy * 16 + q * 4;
#pragma unroll
        for (int r = 0; r < 4; r++)
            A.logits[(size_t)(rr0 + r) * N_ + c] = acc[nt][r] * invn;
    }
}

// P6: addressing tail for one (head,b) row
__device__ void phase6(const MArgs& A, Sh& sh, int row) {
    const int tid = threadIdx.x;
    const int head = row >> 8, b = row & 255;
    const float* w6 = head ? A.w6r : A.w6w;
    const float* bias = head ? A.bhr : A.bhw;
    float* wf = head ? A.wrf : A.wwf;
    float d0 = 0, d1 = 0, d2 = 0, d3 = 0, d4 = 0, d5 = 0, ssq = 0;
#pragma unroll
    for (int j = 0; j < 2; j++) {
        int k = tid + j * 256;
        float hv = tanhf(A.h_acc[(size_t)b * H_ + k] + A.xwx_cur[(size_t)b * H_ + k] + A.bh[k]);
        const float* wk = w6 + k * 6;
        d0 += hv * wk[0]; d1 += hv * wk[1]; d2 += hv * wk[2];
        d3 += hv * wk[3]; d4 += hv * wk[4]; d5 += hv * wk[5];
        size_t ki = (size_t)row * M_ + k;
        float kv = bf2f(A.kh[ki]) + bf2f(A.kh[PL_KH + ki]);
        ssq += kv * kv;
    }
    d0 = block_sum_(d0, sh.red); d1 = block_sum_(d1, sh.red); d2 = block_sum_(d2, sh.red);
    d3 = block_sum_(d3, sh.red); d4 = block_sum_(d4, sh.red); d5 = block_sum_(d5, sh.red);
    ssq = block_sum_(ssq, sh.red);
    float beta = softplus_(d0 + bias[M_]);
    float g = sigm_(d1 + bias[M_ + 1]);
    float a0s = d2 + bias[M_ + 2], a1s = d3 + bias[M_ + 3], a2s = d4 + bias[M_ + 4];
    float mx3 = fmaxf(a0s, fmaxf(a1s, a2s));
    float e0 = expf(a0s - mx3), e1 = expf(a1s - mx3), e2 = expf(a2s - mx3);
    float es = e0 + e1 + e2;
    float s0 = e0 / es, s1 = e1 / es, s2 = e2 / es;
    float gamma = 1.f + softplus_(d5 + bias[M_ + 5]);
    float rowsc = beta / (sqrtf(ssq) + EPS_);
    float4 lv = *(const float4*)&A.logits[(size_t)row * N_ + tid * 4];
    float l[4] = {lv.x * rowsc, lv.y * rowsc, lv.z * rowsc, lv.w * rowsc};
    float mx = fmaxf(fmaxf(l[0], l[1]), fmaxf(l[2], l[3]));
    mx = block_max_(mx, sh.red);
    float ex[4], sum = 0.f;
#pragma unroll
    for (int j = 0; j < 4; j++) { ex[j] = expf(l[j] - mx); sum += ex[j]; }
    sum = block_sum_(sum, sh.red);
    float inv = 1.f / sum;
    float4 wpv = *(const float4*)&wf[(size_t)b * N_ + tid * 4];
    float wprev[4] = {wpv.x, wpv.y, wpv.z, wpv.w};
#pragma unroll
    for (int j = 0; j < 4; j++) sh.wgs[tid * 4 + j] = g * ex[j] * inv + (1.f - g) * wprev[j];
    __syncthreads();
    float wp[4], psum = 0.f;
#pragma unroll
    for (int j = 0; j < 4; j++) {
        int n = tid * 4 + j;
        float wt = s0 * sh.wgs[(n + 1) & (N_ - 1)] + s1 * sh.wgs[n] + s2 * sh.wgs[(n - 1) & (N_ - 1)];
        float v = expf(gamma * logf(wt));
        wp[j] = v; psum += v;
    }
    psum = block_sum_(psum, sh.red);
    float invp = 1.f / (psum + EPS_);
#pragma unroll
    for (int j = 0; j < 4; j++) {
        int n = tid * 4 + j;
        float val = wp[j] * invp;
        wf[(size_t)b * N_ + n] = val;
        if (head == 0) {
            u16 h, m; split2(val, h, m);
            size_t tb = (size_t)n * B_ + b;
            A.wwT_pl[tb] = h; A.wwT_pl[PL_W + tb] = m;
        }
    }
}

// ================= cooperative mega-kernel =================
__global__ __launch_bounds__(256, 2) void ntm_mega(MArgs A) {
    cg::grid_group grid = cg::this_grid();
    __shared__ Sh sh;
    const int NB = gridDim.x;
    for (int t = 0; t < T_; t++) {
        for (int u = blockIdx.x; u < 512; u += NB) phase1(A, sh, u, t);
        grid.sync();
        for (int u = blockIdx.x; u < 256; u += NB) phase2(A, sh, u);
        grid.sync();
        for (int u = blockIdx.x; u < 256; u += NB) phase3(A, sh, u);
        grid.sync();
        for (int u = blockIdx.x; u < 320; u += NB) phase4(A, sh, u, t);
        grid.sync();
        for (int u = blockIdx.x; u < 256; u += NB) phase5(A, sh, u);
        grid.sync();
        for (int u = blockIdx.x; u < 512; u += NB) phase6(A, sh, u);
        grid.sync();
    }
}

// ================= non-cooperative fallback: one phase per launch =================
__global__ __launch_bounds__(256) void ntm_phase(MArgs A, int t, int ph) {
    __shared__ Sh sh;
    switch (ph) {
    case 1: for (int u = blockIdx.x; u < 512; u += gridDim.x) phase1(A, sh, u, t); break;
    case 2: for (int u = blockIdx.x; u < 256; u += gridDim.x) phase2(A, sh, u); break;
    case 3: for (int u = blockIdx.x; u < 256; u += gridDim.x) phase3(A, sh, u); break;
    case 4: for (int u = blockIdx.x; u < 320; u += gridDim.x) phase4(A, sh, u, t); break;
    case 5: for (int u = blockIdx.x; u < 256; u += gridDim.x) phase5(A, sh, u); break;
    case 6: for (int u = blockIdx.x; u < 512; u += gridDim.x) phase6(A, sh, u); break;
    }
}

// ================= prologue kernels (once per call) =================
struct EpiEA0 {
    const float* bea; u16* eT; u16* aT;
    __device__ void operator()(int r0, int c, v4f v) const {
#pragma unroll
        for (int r = 0; r < 4; r++) {
            float val = v[r] + bea[c];
            u16* dst;
            int b = r0 + r;
            if (c < M_) { val = sigm_(val); dst = eT + (size_t)c * B_ + b; }
            else        { val = tanhf(val); dst = aT + (size_t)(c - M_) * B_ + b; }
            u16 h, m; split2(val, h, m);
            dst[0] = h; dst[PL_H] = m;
        }
    }
};

template <int TM, class Epi>
__global__ __launch_bounds__(256) void gemm2(const u16* __restrict__ Ap, int lda, int apl,
                                             const u16* __restrict__ Bp, int ldb, int bpl,
                                             int K, Epi epi) {
    constexpr int AL = (TM * 32 * 2) / (256 * 8);
    constexpr int MT = TM / 32;
    __shared__ u16 As[2][TM][40];
    __shared__ u16 Bs[2][64][40];
    const int tid = threadIdx.x, lane = tid & 63, w = tid >> 6;
    const int wy = w >> 1, wx = w & 1, q = lane >> 4, l15 = lane & 15;
    const int row0 = blockIdx.y * TM, col0 = blockIdx.x * 64;
    uint4 ra[AL], rb[2];
    auto loadA = [&](int k0) {
#pragma unroll
        for (int j = 0; j < AL; j++) {
            int s = j * 256 + tid, p = s / (TM * 4), rr = (s >> 2) % TM, kg = s & 3;
            ra[j] = *(const uint4*)(Ap + (size_t)p * apl + (size_t)(row0 + rr) * lda + k0 + kg * 8);
        }
    };
    auto loadB = [&](int k0) {
#pragma unroll
        for (int j = 0; j < 2; j++) {
            int s = j * 256 + tid, p = s >> 8, rr = (s >> 2) & 63, kg = s & 3;
            rb[j] = *(const uint4*)(Bp + (size_t)p * bpl + (size_t)(col0 + rr) * ldb + k0 + kg * 8);
        }
    };
    v4f acc[MT][2] = {};
    loadA(0); loadB(0);
    for (int k0 = 0; k0 < K; k0 += 32) {
#pragma unroll
        for (int j = 0; j < AL; j++) {
            int s = j * 256 + tid, p = s / (TM * 4), rr = (s >> 2) % TM, kg = s & 3;
            *(uint4*)&As[p][rr][kg * 8] = ra[j];
        }
#pragma unroll
        for (int j = 0; j < 2; j++) {
            int s = j * 256 + tid, p = s >> 8, rr = (s >> 2) & 63, kg = s & 3;
            *(uint4*)&Bs[p][rr][kg * 8] = rb[j];
        }
        __syncthreads();
        if (k0 + 32 < K) { loadA(k0 + 32); loadB(k0 + 32); }
        v8s af[MT][2], bf[2][2];
#pragma unroll
        for (int mt = 0; mt < MT; mt++) {
            af[mt][0] = *(const v8s*)&As[0][wy * (TM / 2) + mt * 16 + l15][q * 8];
            af[mt][1] = *(const v8s*)&As[1][wy * (TM / 2) + mt * 16 + l15][q * 8];
        }
#pragma unroll
        for (int nt = 0; nt < 2; nt++) {
            bf[nt][0] = *(const v8s*)&Bs[0][wx * 32 + nt * 16 + l15][q * 8];
            bf[nt][1] = *(const v8s*)&Bs[1][wx * 32 + nt * 16 + l15][q * 8];
        }
#pragma unroll
        for (int mt = 0; mt < MT; mt++)
#pragma unroll
            for (int nt = 0; nt < 2; nt++) {
                v4f c = acc[mt][nt];
                c = MFMA(af[mt][0], bf[nt][0], c);
                c = MFMA(af[mt][0], bf[nt][1], c);
                c = MFMA(af[mt][1], bf[nt][0], c);
                acc[mt][nt] = c;
            }
        __syncthreads();
    }
#pragma unroll
    for (int mt = 0; mt < MT; mt++)
#pragma unroll
        for (int nt = 0; nt < 2; nt++)
            epi(row0 + wy * (TM / 2) + mt * 16 + q * 4, col0 + wx * 32 + nt * 16 + l15, acc[mt][nt]);
}

__global__ __launch_bounds__(256) void gemm2_xwx(const float* __restrict__ x, const u16* __restrict__ WxT,
                                                 float* __restrict__ outbuf) {
    __shared__ u16 As[2][64][40];
    __shared__ u16 Bs[2][64][40];
    const int tid = threadIdx.x, lane = tid & 63, w = tid >> 6;
    const int wy = w >> 1, wx = w & 1, q = lane >> 4, l15 = lane & 15;
    const int row0 = blockIdx.y * 64, col0 = blockIdx.x * 64;
    const int sr = tid >> 2, ss = (tid & 3) * 8;
    const int arow = row0 + sr, ab = arow & 255, at = arow >> 8;
    const float* Asrc = x + ((size_t)ab * T_ + at) * I_ + ss;
    v4f acc[2][2] = {};
    for (int k0 = 0; k0 < I_; k0 += 32) {
        float4 f0 = *(const float4*)(Asrc + k0);
        float4 f1 = *(const float4*)(Asrc + k0 + 4);
        float av8[8] = {f0.x, f0.y, f0.z, f0.w, f1.x, f1.y, f1.z, f1.w};
#pragma unroll
        for (int j = 0; j < 8; j++) {
            u16 h, m; split2(av8[j], h, m);
            As[0][sr][ss + j] = h; As[1][sr][ss + j] = m;
        }
#pragma unroll
        for (int p = 0; p < 2; p++)
            *(uint4*)&Bs[p][sr][ss] = *(const uint4*)&WxT[(size_t)p * PL_WXT + (size_t)(col0 + sr) * I_ + k0 + ss];
        __syncthreads();
        v8s af[2][2], bf[2][2];
#pragma unroll
        for (int mt = 0; mt < 2; mt++) {
            af[mt][0] = *(const v8s*)&As[0][wy * 32 + mt * 16 + l15][q * 8];
            af[mt][1] = *(const v8s*)&As[1][wy * 32 + mt * 16 + l15][q * 8];
            bf[mt][0] = *(const v8s*)&Bs[0][wx * 32 + mt * 16 + l15][q * 8];
            bf[mt][1] = *(const v8s*)&Bs[1][wx * 32 + mt * 16 + l15][q * 8];
        }
#pragma unroll
        for (int mt = 0; mt < 2; mt++)
#pragma unroll
            for (int nt = 0; nt < 2; nt++) {
                v4f c = acc[mt][nt];
                c = MFMA(af[mt][0], bf[nt][0], c);
                c = MFMA(af[mt][0], bf[nt][1], c);
                c = MFMA(af[mt][1], bf[nt][0], c);
                acc[mt][nt] = c;
            }
        __syncthreads();
    }
#pragma unroll
    for (int mt = 0; mt < 2; mt++)
#pragma unroll
        for (int nt = 0; nt < 2; nt++) {
            int r0 = row0 + wy * 32 + mt * 16 + q * 4;
            int c  = col0 + wx * 32 + nt * 16 + l15;
#pragma unroll
            for (int r = 0; r < 4; r++) {
                int row = r0 + r, b = row & 255, t = row >> 8;
                outbuf[((size_t)b * T_ + t) * O_ + c] = acc[mt][nt][r];
            }
        }
}

__global__ __launch_bounds__(256) void decomp_t(const float* __restrict__ in, int ldin, int c0,
                                                int R, u16* __restrict__ outp, int opl) {
    __shared__ float Ls[32][33];
    const int r0 = blockIdx.x * 32, cB = blockIdx.y * 32;
    const int tid = threadIdx.x;
    int lr = tid >> 3, lc = (tid & 7) * 4;
#pragma unroll
    for (int j = 0; j < 4; j++)
        Ls[lr][lc + j] = in[(size_t)(r0 + lr) * ldin + c0 + cB + lc + j];
    __syncthreads();
    int lc2 = tid >> 3, lr2 = (tid & 7) * 4;
    u16 hv[4], mv[4];
#pragma unroll
    for (int j = 0; j < 4; j++) split2(Ls[lr2 + j][lc2], hv[j], mv[j]);
    size_t base = (size_t)(cB + lc2) * R + r0 + lr2;
    *(ushort4*)&outp[0 * (size_t)opl + base] = make_ushort4(hv[0], hv[1], hv[2], hv[3]);
    *(ushort4*)&outp[1 * (size_t)opl + base] = make_ushort4(mv[0], mv[1], mv[2], mv[3]);
}

__global__ __launch_bounds__(512) void wh6_kernel(const float* __restrict__ Whw, const float* __restrict__ Whr,
                                                  float* __restrict__ w6w, float* __restrict__ w6r) {
    int k = threadIdx.x;
    const float* src = blockIdx.x ? Whr : Whw;
    float* dst = blockIdx.x ? w6r : w6w;
#pragma unroll
    for (int j = 0; j < 6; j++) dst[k * 6 + j] = src[(size_t)k * (M_ + 6) + M_ + j];
}
__global__ __launch_bounds__(256) void init_mem(const float* __restrict__ mem0, float* __restrict__ memf,
                                                u16* __restrict__ mem_pl, u16* __restrict__ memT_pl) {
    int n = blockIdx.x;
    for (int c = threadIdx.x; c < M_; c += 256) {
        float v = mem0[(size_t)n * M_ + c];
        size_t idx = (size_t)n * M_ + c;
        memf[idx] = v;
        u16 h, m; split2(v, h, m);
        mem_pl[idx] = h; mem_pl[PL_MEM + idx] = m;
        size_t tb = (size_t)c * N_ + n;
        memT_pl[tb] = h; memT_pl[PL_MEM + tb] = m;
    }
}
__global__ __launch_bounds__(256) void init_w(const float* __restrict__ wr0, const float* __restrict__ ww0,
                                              float* __restrict__ wrf, float* __restrict__ wwf,
                                              u16* __restrict__ wwT_pl) {
    int b = blockIdx.x;
    for (int n = threadIdx.x; n < N_; n += 256) {
        size_t idx = (size_t)b * N_ + n;
        float vw = ww0[idx]; wwf[idx] = vw;
        u16 h, m; split2(vw, h, m);
        size_t tb = (size_t)n * B_ + b;
        wwT_pl[tb] = h; wwT_pl[PL_W + tb] = m;
        wrf[idx] = wr0[idx];
    }
}
__global__ __launch_bounds__(64) void init_h(const float* __restrict__ h0, u16* __restrict__ hp) {
    int b = blockIdx.x;
    for (int c = threadIdx.x; c < H_; c += 64) {
        size_t idx = (size_t)b * H_ + c;
        u16 h, m; split2(h0[idx], h, m);
        hp[idx] = h; hp[PL_H + idx] = m;
    }
}

// ================= host =================
extern "C" void kernel_launch(void* const* d_in, const int* in_sizes, int n_in,
                              void* d_out, int out_size, void* d_ws, size_t ws_size,
                              hipStream_t stream) {
    (void)in_sizes; (void)n_in; (void)out_size; (void)ws_size;
    const float* x    = (const float*)d_in[0];
    const float* mem0 = (const float*)d_in[1];
    const float* wr0  = (const float*)d_in[2];
    const float* ww0  = (const float*)d_in[3];
    const float* h0   = (const float*)d_in[4];
    const float* Wx   = (const float*)d_in[5];
    const float* Wr   = (const float*)d_in[6];
    const float* bh   = (const float*)d_in[7];
    const float* Whr  = (const float*)d_in[8];
    const float* bhr  = (const float*)d_in[9];
    const float* Whw  = (const float*)d_in[10];
    const float* bhw  = (const float*)d_in[11];
    const float* Wea  = (const float*)d_in[12];
    const float* bea  = (const float*)d_in[13];
    const float* Wo   = (const float*)d_in[14];
    const float* bo   = (const float*)d_in[15];
    float* out = (float*)d_out;

    char* wsb = (char*)d_ws;
    size_t off = 0;
    auto carveU = [&](size_t elems) { u16* p = (u16*)(wsb + off); off += elems * sizeof(u16); return p; };
    u16* BigT    = carveU(2 * (size_t)PL_BIG);
    u16* WxT     = carveU(2 * (size_t)PL_WXT);
    u16* WrT     = carveU(2 * (size_t)PL_WRT);
    u16* mem_pl  = carveU(2 * (size_t)PL_MEM);
    u16* memT_pl = carveU(2 * (size_t)PL_MEM);
    u16* wwT_pl  = carveU(2 * (size_t)PL_W);
    u16* h_pl    = carveU(2 * (size_t)PL_H);
    u16* eT_pl   = carveU(2 * (size_t)PL_H);
    u16* aT_pl   = carveU(2 * (size_t)PL_H);
    u16* kh_pl   = carveU(2 * (size_t)PL_KH);
    auto carveF = [&](size_t elems) { float* p = (float*)(wsb + off); off += elems * sizeof(float); return p; };
    float* memf    = carveF((size_t)N_ * M_);
    float* wwf     = carveF((size_t)B_ * N_);
    float* wrf     = carveF((size_t)B_ * N_);
    float* r_acc   = carveF((size_t)B_ * M_);
    float* h_acc   = carveF((size_t)B_ * H_);
    float* xwx_cur = carveF((size_t)B_ * H_);
    float* logits  = carveF((size_t)2 * B_ * N_);
    float* ssqp    = carveF((size_t)N_ * 8);
    float* w6w     = carveF(H_ * 6);
    float* w6r     = carveF(H_ * 6);

    // prologue: weight decomposition + state init
    decomp_t<<<dim3(16, 16), 256, 0, stream>>>(Whw, M_ + 6, 0, 512, BigT, PL_BIG);
    decomp_t<<<dim3(16, 16), 256, 0, stream>>>(Whr, M_ + 6, 0, 512, BigT + (size_t)512 * 512, PL_BIG);
    decomp_t<<<dim3(16, 16), 256, 0, stream>>>(Wo, 512, 0, 512, BigT + (size_t)1024 * 512, PL_BIG);
    decomp_t<<<dim3(16, 32), 256, 0, stream>>>(Wea, 1024, 0, 512, BigT + (size_t)1536 * 512, PL_BIG);
    decomp_t<<<dim3(16, 16), 256, 0, stream>>>(Wx, 512, 0, 512, WxT, PL_WXT);
    decomp_t<<<dim3(16, 16), 256, 0, stream>>>(Wr, 512, 0, 512, WrT, PL_WRT);
    wh6_kernel<<<2, 512, 0, stream>>>(Whw, Whr, w6w, w6r);
    init_mem<<<N_, 256, 0, stream>>>(mem0, memf, mem_pl, memT_pl);
    init_w<<<B_, 256, 0, stream>>>(wr0, ww0, wrf, wwf, wwT_pl);
    init_h<<<B_, 64, 0, stream>>>(h0, h_pl);
    gemm2_xwx<<<dim3(8, 512), 256, 0, stream>>>(x, WxT, out);
    gemm2<32, EpiEA0><<<dim3(16, 8), 256, 0, stream>>>(
        h_pl, 512, PL_H, BigT + (size_t)1536 * 512, 512, PL_BIG, 512, EpiEA0{bea, eT_pl, aT_pl});

    MArgs ma;
    ma.bea = bea; ma.bh = bh; ma.bhw = bhw; ma.bhr = bhr; ma.bo = bo; ma.w6w = w6w; ma.w6r = w6r;
    ma.BigT = BigT; ma.WrT = WrT;
    ma.mem_pl = mem_pl; ma.memT_pl = memT_pl; ma.wwT_pl = wwT_pl; ma.eT = eT_pl; ma.aT = aT_pl; ma.kh = kh_pl;
    ma.memf = memf; ma.wwf = wwf; ma.wrf = wrf; ma.r_acc = r_acc; ma.h_acc = h_acc;
    ma.xwx_cur = xwx_cur; ma.logits = logits; ma.ssqp = ssqp; ma.outbuf = out;

    // cooperative path, occupancy-guarded; deterministic fallback to per-phase launches
    int maxB = 0;
    hipError_t qerr = hipOccupancyMaxActiveBlocksPerMultiprocessor(&maxB, ntm_mega, 256, 0);
    bool coop = false;
    if (qerr == hipSuccess && maxB >= 1) {
        int nb = (maxB >= 2) ? 512 : 256;
        void* kargs[1] = {&ma};
        hipError_t lerr = hipLaunchCooperativeKernel(ntm_mega, dim3(nb), dim3(256), kargs, 0, stream);
        if (lerr == hipSuccess) coop = true;
        else (void)hipGetLastError();  // clear sticky error before fallback
    } else {
        (void)hipGetLastError();
    }
    if (!coop) {
        for (int t = 0; t < T_; t++)
            for (int ph = 1; ph <= 6; ph++)
                ntm_phase<<<512, 256, 0, stream>>>(ma, t, ph);
    }
}